// Round 1
// baseline (236.515 us; speedup 1.0000x reference)
//
#include <hip/hip_runtime.h>

// filtfilt (4th-order IIR, 5-tap FIR) over 512 independent sequences of 48000.
// One block (1024 threads) per sequence; chunk-scan parallelization of the
// linear recurrence in both directions; forward output stays in registers.
// Scale normalization of the reference is skipped (linear, cancels exactly).

#define T48   48000
#define LCH   48          // samples per thread-chunk
#define NCH   1024        // chunks per sequence (NCH*LCH = 49152 >= 48030)
#define TP0   48030       // true padded length (48000 + 2*15)

__device__ __forceinline__ float padfetch(const float* __restrict__ xs, int p) {
  // xp[p] of the odd-extended sequence; zero outside [0, TP0)
  if (p < 0)        return 0.f;
  if (p < 15)       return 2.f * xs[0] - xs[14 - p];
  if (p < T48 + 15) return xs[p - 15];
  if (p < T48 + 30) return 2.f * xs[T48 - 1] - xs[2 * T48 + 12 - p];
  return 0.f;
}

// one IIR step: u = f - a1*r1 - a2*r2 - a3*r3 - a4*r4 ; shift state
#define RECUR_STEP(fv, arr, idx)                                                \
  do {                                                                          \
    float u_ = fmaf(na4, r4, (fv));                                             \
    u_ = fmaf(na3, r3, u_); u_ = fmaf(na2, r2, u_); u_ = fmaf(na1, r1, u_);     \
    arr[idx] = u_; r4 = r3; r3 = r2; r2 = r1; r1 = u_;                          \
  } while (0)

__global__ __launch_bounds__(1024, 4) void filtfilt_k(
    const float* __restrict__ x, const float* __restrict__ bco,
    const float* __restrict__ aco, float* __restrict__ out)
{
  __shared__ float Sb[2][NCH][4];   // ping-pong scan buffers
  __shared__ float P[10][16];       // P[k] = M^(2^k), row-major 4x4
  __shared__ float heads[NCH][4];   // first 4 forward outputs per chunk
  __shared__ float stitch[NCH];     // z[0] per chunk for output stitching

  const int c = threadIdx.x;
  const float* __restrict__ xs = x + (size_t)blockIdx.x * T48;
  float* __restrict__ os = out + (size_t)blockIdx.x * T48;

  const float inva0 = 1.f / aco[0];
  const float b0 = bco[0]*inva0, b1 = bco[1]*inva0, b2 = bco[2]*inva0,
              b3 = bco[3]*inva0, b4 = bco[4]*inva0;
  const float na1 = -aco[1]*inva0, na2 = -aco[2]*inva0,
              na3 = -aco[3]*inva0, na4 = -aco[4]*inva0;

  // ---------- prologue: M = 48-step state transition, then repeated squaring
  if (c < 4) {
    float r1 = (c==0)?1.f:0.f, r2 = (c==1)?1.f:0.f,
          r3 = (c==2)?1.f:0.f, r4 = (c==3)?1.f:0.f;
#pragma unroll
    for (int n = 0; n < LCH; n++) {
      float h = fmaf(na1, r1, fmaf(na2, r2, fmaf(na3, r3, na4 * r4)));
      r4 = r3; r3 = r2; r2 = r1; r1 = h;
    }
    // column c of M: rows are state comps (y[47],y[46],y[45],y[44])
    P[0][0*4+c] = r1; P[0][1*4+c] = r2; P[0][2*4+c] = r3; P[0][3*4+c] = r4;
  }
  __syncthreads();
#pragma unroll
  for (int k = 0; k < 9; k++) {
    float v = 0.f;
    if (c < 16) {
      const int i = c >> 2, j = c & 3;
      v = P[k][i*4+0]*P[k][0*4+j] + P[k][i*4+1]*P[k][1*4+j]
        + P[k][i*4+2]*P[k][2*4+j] + P[k][i*4+3]*P[k][3*4+j];
    }
    if (c < 16) P[k+1][c] = v;
    __syncthreads();
  }

  // ---------- forward pass, phase 1: FIR + zero-state recursion
  float y[LCH];
  float r1 = 0.f, r2 = 0.f, r3 = 0.f, r4 = 0.f;
  if (c >= 1 && c <= 999) {
    // whole chunk is interior: xp[48c+q] = xs[48c+q-15]; need q in [-4,48)
    // load aligned float4s covering xs[48c-20 .. 48c+36)
    const float4* __restrict__ xp4 = reinterpret_cast<const float4*>(xs + 48*c - 20);
    float4 pv = xp4[0];
#pragma unroll
    for (int j = 1; j < 14; j++) {
      const float4 t = xp4[j];
      // group j provides xv[4j..4j+4); enables n = 4j-5 .. 4j-2 (xv idx = n+5-k)
      if (4*j-5 >= 0 && 4*j-5 < LCH) {
        float f = fmaf(b0,t.x, fmaf(b1,pv.w, fmaf(b2,pv.z, fmaf(b3,pv.y, b4*pv.x))));
        RECUR_STEP(f, y, 4*j-5);
      }
      if (4*j-4 >= 0 && 4*j-4 < LCH) {
        float f = fmaf(b0,t.y, fmaf(b1,t.x, fmaf(b2,pv.w, fmaf(b3,pv.z, b4*pv.y))));
        RECUR_STEP(f, y, 4*j-4);
      }
      if (4*j-3 >= 0 && 4*j-3 < LCH) {
        float f = fmaf(b0,t.z, fmaf(b1,t.y, fmaf(b2,t.x, fmaf(b3,pv.w, b4*pv.z))));
        RECUR_STEP(f, y, 4*j-3);
      }
      if (4*j-2 >= 0 && 4*j-2 < LCH) {
        float f = fmaf(b0,t.w, fmaf(b1,t.z, fmaf(b2,t.y, fmaf(b3,t.x, b4*pv.w))));
        RECUR_STEP(f, y, 4*j-2);
      }
      pv = t;
    }
  } else if (c == 0 || c == 1000) {
    // boundary chunks: scalar rolling window with padding map (no OOB)
    float w1 = padfetch(xs, 48*c - 1), w2 = padfetch(xs, 48*c - 2),
          w3 = padfetch(xs, 48*c - 3), w4 = padfetch(xs, 48*c - 4);
#pragma unroll
    for (int n = 0; n < LCH; n++) {
      float w0 = padfetch(xs, 48*c + n);
      float f = fmaf(b0,w0, fmaf(b1,w1, fmaf(b2,w2, fmaf(b3,w3, b4*w4))));
      RECUR_STEP(f, y, n);
      w4 = w3; w3 = w2; w2 = w1; w1 = w0;
    }
  } else {
    // c > 1000: entirely in the zero-extended tail
#pragma unroll
    for (int n = 0; n < LCH; n++) y[n] = 0.f;
  }

  // ---------- forward scan over chunk states
  {
    Sb[0][c][0] = r1; Sb[0][c][1] = r2; Sb[0][c][2] = r3; Sb[0][c][3] = r4;
    __syncthreads();
#pragma unroll
    for (int k = 0; k < 10; k++) {
      const int off = 1 << k, cu = k & 1, nx = cu ^ 1;
      float t0 = Sb[cu][c][0], t1 = Sb[cu][c][1], t2 = Sb[cu][c][2], t3 = Sb[cu][c][3];
      if (c >= off) {
        float q0 = Sb[cu][c-off][0], q1 = Sb[cu][c-off][1],
              q2 = Sb[cu][c-off][2], q3 = Sb[cu][c-off][3];
        t0 += P[k][0]*q0  + P[k][1]*q1  + P[k][2]*q2  + P[k][3]*q3;
        t1 += P[k][4]*q0  + P[k][5]*q1  + P[k][6]*q2  + P[k][7]*q3;
        t2 += P[k][8]*q0  + P[k][9]*q1  + P[k][10]*q2 + P[k][11]*q3;
        t3 += P[k][12]*q0 + P[k][13]*q1 + P[k][14]*q2 + P[k][15]*q3;
      }
      Sb[nx][c][0] = t0; Sb[nx][c][1] = t1; Sb[nx][c][2] = t2; Sb[nx][c][3] = t3;
      __syncthreads();
    }
  }
  float s0 = 0.f, s1 = 0.f, s2 = 0.f, s3 = 0.f;
  if (c > 0) { s0 = Sb[0][c-1][0]; s1 = Sb[0][c-1][1]; s2 = Sb[0][c-1][2]; s3 = Sb[0][c-1][3]; }

  // ---------- forward phase 2: homogeneous correction
  {
    float h1 = s0, h2 = s1, h3 = s2, h4 = s3;
#pragma unroll
    for (int n = 0; n < LCH; n++) {
      float h = fmaf(na1, h1, fmaf(na2, h2, fmaf(na3, h3, na4 * h4)));
      y[n] += h;
      h4 = h3; h3 = h2; h2 = h1; h1 = h;
    }
  }
  // force exact zero tail (defines the extension; makes backward pass exact)
  if (c == 1000) {
#pragma unroll
    for (int n = 0; n < LCH; n++) if (48000 + n >= TP0) y[n] = 0.f;
  } else if (c > 1000) {
#pragma unroll
    for (int n = 0; n < LCH; n++) y[n] = 0.f;
  }

  // ---------- exchange heads (backward FIR halo)
  heads[c][0] = y[0]; heads[c][1] = y[1]; heads[c][2] = y[2]; heads[c][3] = y[3];
  __syncthreads();   // also orders forward-scan reads vs backward-scan writes
  float hl[4] = {0.f, 0.f, 0.f, 0.f};
  if (c < NCH - 1) { hl[0] = heads[c+1][0]; hl[1] = heads[c+1][1];
                     hl[2] = heads[c+1][2]; hl[3] = heads[c+1][3]; }

  // ---------- backward pass, phase 1 (on own reversed chunk)
#define YV(i) (((i) < LCH) ? y[(i)] : hl[(i) - LCH])
  float z[LCH];
  r1 = 0.f; r2 = 0.f; r3 = 0.f; r4 = 0.f;
#pragma unroll
  for (int m = 0; m < LCH; m++) {
    float g = fmaf(b0, YV(47-m), fmaf(b1, YV(48-m),
              fmaf(b2, YV(49-m), fmaf(b3, YV(50-m), b4 * YV(51-m)))));
    RECUR_STEP(g, z, m);
  }
#undef YV

  // ---------- backward scan (row = reversed chunk index d)
  const int d = NCH - 1 - c;
  {
    Sb[0][d][0] = r1; Sb[0][d][1] = r2; Sb[0][d][2] = r3; Sb[0][d][3] = r4;
    __syncthreads();
#pragma unroll
    for (int k = 0; k < 10; k++) {
      const int off = 1 << k, cu = k & 1, nx = cu ^ 1;
      float t0 = Sb[cu][d][0], t1 = Sb[cu][d][1], t2 = Sb[cu][d][2], t3 = Sb[cu][d][3];
      if (d >= off) {
        float q0 = Sb[cu][d-off][0], q1 = Sb[cu][d-off][1],
              q2 = Sb[cu][d-off][2], q3 = Sb[cu][d-off][3];
        t0 += P[k][0]*q0  + P[k][1]*q1  + P[k][2]*q2  + P[k][3]*q3;
        t1 += P[k][4]*q0  + P[k][5]*q1  + P[k][6]*q2  + P[k][7]*q3;
        t2 += P[k][8]*q0  + P[k][9]*q1  + P[k][10]*q2 + P[k][11]*q3;
        t3 += P[k][12]*q0 + P[k][13]*q1 + P[k][14]*q2 + P[k][15]*q3;
      }
      Sb[nx][d][0] = t0; Sb[nx][d][1] = t1; Sb[nx][d][2] = t2; Sb[nx][d][3] = t3;
      __syncthreads();
    }
  }
  float e0 = 0.f, e1 = 0.f, e2 = 0.f, e3 = 0.f;
  if (d > 0) { e0 = Sb[0][d-1][0]; e1 = Sb[0][d-1][1]; e2 = Sb[0][d-1][2]; e3 = Sb[0][d-1][3]; }

  // ---------- backward phase 2: homogeneous correction
  {
    float h1 = e0, h2 = e1, h3 = e2, h4 = e3;
#pragma unroll
    for (int m = 0; m < LCH; m++) {
      float h = fmaf(na1, h1, fmaf(na2, h2, fmaf(na3, h3, na4 * h4)));
      z[m] += h;
      h4 = h3; h3 = h2; h2 = h1; h1 = h;
    }
  }

  // ---------- stores: out[t] = z at p = t + 15 ; thread c owns p in [48c,48c+48)
  // m = 48c + 32 - t. Aligned float4 groups; z[0] stitched to neighbor c+1.
  stitch[c] = z[0];
  __syncthreads();
  float zp = (c > 0) ? stitch[c-1] : 0.f;
  {
    const int t = 48*c - 16;   // [zp, z[47], z[46], z[45]]
    if (t >= 0 && t <= T48 - 4) {
      float4 v = make_float4(zp, z[47], z[46], z[45]);
      *reinterpret_cast<float4*>(os + t) = v;
    }
  }
#pragma unroll
  for (int k = 0; k < 11; k++) {
    const int t = 48*c - 12 + 4*k;
    const int m0 = 44 - 4*k;
    if (t >= 0 && t <= T48 - 4) {
      float4 v = make_float4(z[m0], z[m0-1], z[m0-2], z[m0-3]);
      *reinterpret_cast<float4*>(os + t) = v;
    }
  }
}

extern "C" void kernel_launch(void* const* d_in, const int* in_sizes, int n_in,
                              void* d_out, int out_size, void* d_ws, size_t ws_size,
                              hipStream_t stream) {
  (void)n_in; (void)d_ws; (void)ws_size; (void)out_size;
  const float* x = (const float*)d_in[0];
  const float* b = (const float*)d_in[1];
  const float* a = (const float*)d_in[2];
  float* out = (float*)d_out;
  const int nseq = in_sizes[0] / T48;   // 8*64 = 512
  filtfilt_k<<<dim3(nseq), dim3(1024), 0, stream>>>(x, b, a, out);
}

// Round 2
// 207.115 us; speedup vs baseline: 1.1419x; 1.1419x over previous
//
#include <hip/hip_runtime.h>

// filtfilt (4th-order IIR, 5-tap FIR) over 512 independent sequences of 48000.
// One 1024-thread block per sequence. V2: coalesced global I/O via swizzled
// LDS staging, in-place single register array (x -> y -> z), wave0-only
// prologue, ping-pong chunk-scan for both directions.

#define T48   48000
#define TP0   48030      // padded true length (48000 + 2*15)
#define LCH   48         // samples per thread-chunk
#define NCH   1024       // chunks per sequence (NCH*LCH = 49152 >= TP0)
#define SECF  12288      // floats per load-section (256 chunks)
#define OSEC  12000      // output floats per store-section
#define UF    12560      // union region size (floats)

__global__ __launch_bounds__(1024, 4) void filtfilt_k(
    const float* __restrict__ x, const float* __restrict__ bco,
    const float* __restrict__ aco, float* __restrict__ out)
{
  __shared__ __align__(16) float U[UF];   // staging / scan buffers / heads
  __shared__ float P[10][16];             // P[k] = M^(2^k), row-major 4x4

  const int c = threadIdx.x;
  const float* __restrict__ xs = x + (size_t)blockIdx.x * T48;
  float* __restrict__ os = out + (size_t)blockIdx.x * T48;

  const float inva0 = 1.f / aco[0];
  const float b0 = bco[0]*inva0, b1 = bco[1]*inva0, b2 = bco[2]*inva0,
              b3 = bco[3]*inva0, b4 = bco[4]*inva0;
  const float na1 = -aco[1]*inva0, na2 = -aco[2]*inva0,
              na3 = -aco[3]*inva0, na4 = -aco[4]*inva0;

  // ---------- prologue (wave 0 only, shuffle-synchronous, no barriers)
  if (c < 64) {
    const int i = (c >> 2) & 3, j = c & 3;
    float r1 = (j==0)?1.f:0.f, r2 = (j==1)?1.f:0.f,
          r3 = (j==2)?1.f:0.f, r4 = (j==3)?1.f:0.f;
#pragma unroll
    for (int n = 0; n < LCH; n++) {   // column j of M = companion^48
      float h = fmaf(na1, r1, fmaf(na2, r2, fmaf(na3, r3, na4 * r4)));
      r4 = r3; r3 = r2; r2 = r1; r1 = h;
    }
    float c0 = __shfl(r1, j), c1 = __shfl(r2, j),
          c2 = __shfl(r3, j), c3 = __shfl(r4, j);
    float Pv = (i==0)?c0 : (i==1)?c1 : (i==2)?c2 : c3;   // M[i][j]
    if (c < 16) P[0][c] = Pv;
#pragma unroll
    for (int k = 0; k < 9; k++) {      // repeated squaring via shuffles
      float rA0 = __shfl(Pv, i*4+0), rA1 = __shfl(Pv, i*4+1),
            rA2 = __shfl(Pv, i*4+2), rA3 = __shfl(Pv, i*4+3);
      float cB0 = __shfl(Pv, 0*4+j), cB1 = __shfl(Pv, 1*4+j),
            cB2 = __shfl(Pv, 2*4+j), cB3 = __shfl(Pv, 3*4+j);
      Pv = rA0*cB0 + rA1*cB1 + rA2*cB2 + rA3*cB3;
      if (c < 16) P[k+1][c] = Pv;
    }
  }

  // ---------- load staging (coalesced global -> swizzled LDS -> registers)
  float A[LCH];
  float w1 = 0.f, w2 = 0.f, w3 = 0.f, w4 = 0.f;
  for (int s = 0; s < 4; s++) {
    __syncthreads();
    const int p0 = SECF * s;
#pragma unroll
    for (int j = 0; j < 13; j++) {
      int i = 1024*j + c;
      if (i < SECF + 4) {
        int p = p0 - 4 + i;            // padded index
        int q = p - 15;                // interior xs index
        float v = 0.f;
        if (q >= 0 && q < T48)               v = xs[q];
        else if (p >= 0 && p < 15)           v = 2.f*xs[0] - xs[14 - p];
        else if (p >= T48+15 && p < TP0)     v = 2.f*xs[T48-1] - xs[2*T48 + 12 - p];
        U[i + i/48] = v;               // swizzle: +1 pad per 48
      }
    }
    __syncthreads();
    if ((c >> 8) == s) {
      const int cl = c & 255;
      const int rb = 49 * cl;
      w4 = U[rb+0]; w3 = U[rb+1]; w2 = U[rb+2]; w1 = U[rb+3];
#pragma unroll
      for (int n = 0; n < LCH; n++) A[n] = U[rb + (n+4) + ((n+4) >> 6 >= 0 ? (n+4)/48 : 0)];
    }
  }
  __syncthreads();   // all extracts done before scan buffers overwrite stage

  // ---------- forward pass, phase 1 (in place, zero-state)
  float r1 = 0.f, r2 = 0.f, r3 = 0.f, r4 = 0.f;
#pragma unroll
  for (int n = 0; n < LCH; n++) {
    float xv = A[n];
    float f = fmaf(b0,xv, fmaf(b1,w1, fmaf(b2,w2, fmaf(b3,w3, b4*w4))));
    w4 = w3; w3 = w2; w2 = w1; w1 = xv;
    float u = fmaf(na4, r4, f);
    u = fmaf(na3, r3, u); u = fmaf(na2, r2, u); u = fmaf(na1, r1, u);
    A[n] = u; r4 = r3; r3 = r2; r2 = r1; r1 = u;
  }

  // ---------- forward chunk-scan (ping-pong float4 in U)
  float4* Sb0 = (float4*)U;
  float4* Sb1 = (float4*)U + 1024;
  Sb0[c] = make_float4(r1, r2, r3, r4);
  __syncthreads();
#pragma unroll
  for (int k = 0; k < 10; k++) {
    float4* cur = (k & 1) ? Sb1 : Sb0;
    float4* nxt = (k & 1) ? Sb0 : Sb1;
    const int off = 1 << k;
    float4 t = cur[c];
    if (c >= off) {
      float4 q = cur[c - off];
      t.x += P[k][0]*q.x  + P[k][1]*q.y  + P[k][2]*q.z  + P[k][3]*q.w;
      t.y += P[k][4]*q.x  + P[k][5]*q.y  + P[k][6]*q.z  + P[k][7]*q.w;
      t.z += P[k][8]*q.x  + P[k][9]*q.y  + P[k][10]*q.z + P[k][11]*q.w;
      t.w += P[k][12]*q.x + P[k][13]*q.y + P[k][14]*q.z + P[k][15]*q.w;
    }
    nxt[c] = t;
    __syncthreads();
  }
  float4 sv = make_float4(0.f,0.f,0.f,0.f);
  if (c > 0) sv = Sb0[c-1];

  // ---------- forward phase 2: homogeneous correction
  {
    float h1 = sv.x, h2 = sv.y, h3 = sv.z, h4 = sv.w;
#pragma unroll
    for (int n = 0; n < LCH; n++) {
      float h = fmaf(na1, h1, fmaf(na2, h2, fmaf(na3, h3, na4 * h4)));
      A[n] += h;
      h4 = h3; h3 = h2; h2 = h1; h1 = h;
    }
  }
  // exact zero tail past TP0 (defines the extension; backward state = 0 there)
  if (c >= 1000) {
#pragma unroll
    for (int n = 0; n < LCH; n++) if (48*c + n >= TP0) A[n] = 0.f;
  }

  // ---------- exchange heads (backward FIR halo) via Sb1 region
  Sb1[c] = make_float4(A[0], A[1], A[2], A[3]);
  __syncthreads();
  float h0 = 0.f, h1v = 0.f, h2v = 0.f, h3v = 0.f;
  if (c < NCH - 1) { float4 hv = Sb1[c+1]; h0 = hv.x; h1v = hv.y; h2v = hv.z; h3v = hv.w; }

  // ---------- backward phase 1 (own chunk reversed, in place)
#define YV(i) ((i) < 48 ? A[(i)] : ((i)==48 ? h0 : (i)==49 ? h1v : (i)==50 ? h2v : h3v))
  r1 = 0.f; r2 = 0.f; r3 = 0.f; r4 = 0.f;
#pragma unroll
  for (int m = 0; m < LCH; m++) {
    float g = fmaf(b0, YV(47-m), fmaf(b1, YV(48-m),
              fmaf(b2, YV(49-m), fmaf(b3, YV(50-m), b4 * YV(51-m)))));
    float u = fmaf(na4, r4, g);
    u = fmaf(na3, r3, u); u = fmaf(na2, r2, u); u = fmaf(na1, r1, u);
    r4 = r3; r3 = r2; r2 = r1; r1 = u;
    if      (m == 0) h3v = u;
    else if (m == 1) h2v = u;
    else if (m == 2) h1v = u;
    else if (m == 3) h0  = u;
    else             A[51 - m] = u;
  }
#undef YV

  // ---------- backward chunk-scan (element index d = reversed chunk)
  const int d = NCH - 1 - c;
  Sb0[d] = make_float4(r1, r2, r3, r4);
  __syncthreads();
#pragma unroll
  for (int k = 0; k < 10; k++) {
    float4* cur = (k & 1) ? Sb1 : Sb0;
    float4* nxt = (k & 1) ? Sb0 : Sb1;
    const int off = 1 << k;
    float4 t = cur[d];
    if (d >= off) {
      float4 q = cur[d - off];
      t.x += P[k][0]*q.x  + P[k][1]*q.y  + P[k][2]*q.z  + P[k][3]*q.w;
      t.y += P[k][4]*q.x  + P[k][5]*q.y  + P[k][6]*q.z  + P[k][7]*q.w;
      t.z += P[k][8]*q.x  + P[k][9]*q.y  + P[k][10]*q.z + P[k][11]*q.w;
      t.w += P[k][12]*q.x + P[k][13]*q.y + P[k][14]*q.z + P[k][15]*q.w;
    }
    nxt[d] = t;
    __syncthreads();
  }
  float4 ev = make_float4(0.f,0.f,0.f,0.f);
  if (d > 0) ev = Sb0[d-1];

  // ---------- backward phase 2: homogeneous correction into z slots
  {
    float g1 = ev.x, g2 = ev.y, g3 = ev.z, g4 = ev.w;
#pragma unroll
    for (int m = 0; m < LCH; m++) {
      float h = fmaf(na1, g1, fmaf(na2, g2, fmaf(na3, g3, na4 * g4)));
      if      (m == 0) h3v += h;
      else if (m == 1) h2v += h;
      else if (m == 2) h1v += h;
      else if (m == 3) h0  += h;
      else             A[51 - m] += h;
      g4 = g3; g3 = g2; g2 = g1; g1 = h;
    }
  }

  // ---------- store staging (swizzled LDS -> coalesced global)
  // out[t] = z[m] with m = 48c+32-t; thread c covers t in [48c-15, 48c+33)
  __syncthreads();   // protect stage region vs e-reads
  const int tb = 48*c - 15;
  const int sA = (tb < 0 ? 0 : tb / OSEC);
  const int sB = (tb + 47) / OSEC;
  for (int s = 0; s < 4; s++) {
    const int t0 = OSEC * s;
    if (s == sA || s == sB) {
      const int RL49 = 49 * (c - 250*s);
      const int ibase = tb - t0;
#pragma unroll
      for (int k = 0; k < 48; k++) {
        int i = ibase + k;
        if ((unsigned)i < (unsigned)OSEC) {
          // z[47-k]: k<44 -> A[k+4]; else h0..h3v
          float v = (k < 44) ? A[k+4]
                  : (k == 44) ? h0 : (k == 45) ? h1v : (k == 46) ? h2v : h3v;
          U[RL49 + k - 15 - (k < 15 ? 1 : 0)] = v;
        }
      }
    }
    __syncthreads();
#pragma unroll
    for (int j = 0; j < 12; j++) {
      int i = 1024*j + c;
      if (i < OSEC) os[t0 + i] = U[i + i/48];
    }
    __syncthreads();
  }
}

extern "C" void kernel_launch(void* const* d_in, const int* in_sizes, int n_in,
                              void* d_out, int out_size, void* d_ws, size_t ws_size,
                              hipStream_t stream) {
  (void)n_in; (void)d_ws; (void)ws_size; (void)out_size;
  const float* x = (const float*)d_in[0];
  const float* b = (const float*)d_in[1];
  const float* a = (const float*)d_in[2];
  float* out = (float*)d_out;
  const int nseq = in_sizes[0] / T48;   // 512
  filtfilt_k<<<dim3(nseq), dim3(1024), 0, stream>>>(x, b, a, out);
}

// Round 3
// 204.650 us; speedup vs baseline: 1.1557x; 1.0120x over previous
//
#include <hip/hip_runtime.h>

// filtfilt (4th-order IIR, 5-tap FIR) over 512 independent sequences of 48000.
// One 1024-thread block per sequence. V3: all LDS staging in float4 rows of
// 12 (+1 float4 pad) -> b128 LDS ops at odd float4 stride (conflict-free);
// global loads pre-issued one section ahead; dwordx4 global stores; in-place
// register array (x -> y -> z); ping-pong chunk-scan both directions.

#define T48 48000
#define TP0 48030      // padded true length (48000 + 2*15)
#define LCH 48
#define NCH 1024
#define UF  13344      // union region (floats): load-stage needs 13320

__device__ __forceinline__ float fget(const float4& v, int e) {
  switch (e & 3) { case 0: return v.x; case 1: return v.y; case 2: return v.z; default: return v.w; }
}

__global__ __launch_bounds__(1024, 4) void filtfilt_k(
    const float* __restrict__ x, const float* __restrict__ bco,
    const float* __restrict__ aco, float* __restrict__ out)
{
  __shared__ __align__(16) float U[UF];
  __shared__ float P[10][16];             // P[k] = M^(2^k), row-major 4x4

  const int c = threadIdx.x;
  const float* __restrict__ xs = x + (size_t)blockIdx.x * T48;
  const float4* __restrict__ xs4 = reinterpret_cast<const float4*>(xs);
  float* __restrict__ os = out + (size_t)blockIdx.x * T48;
  float4* __restrict__ os4 = reinterpret_cast<float4*>(os);
  float4* __restrict__ U4 = reinterpret_cast<float4*>(U);

  const float inva0 = 1.f / aco[0];
  const float b0 = bco[0]*inva0, b1 = bco[1]*inva0, b2 = bco[2]*inva0,
              b3 = bco[3]*inva0, b4 = bco[4]*inva0;
  const float na1 = -aco[1]*inva0, na2 = -aco[2]*inva0,
              na3 = -aco[3]*inva0, na4 = -aco[4]*inva0;

  // ---------- pre-issue global loads for section 0
  float4 R[4];
#pragma unroll
  for (int j = 0; j < 4; j++) {
    int g = 1024*j + c;
    if (g < 3074) { int m = min(max(g - 5, 0), 11999); R[j] = xs4[m]; }
  }

  // ---------- prologue (wave 0 only, shuffle-synchronous)
  if (c < 64) {
    const int i = (c >> 2) & 3, j = c & 3;
    float r1 = (j==0)?1.f:0.f, r2 = (j==1)?1.f:0.f,
          r3 = (j==2)?1.f:0.f, r4 = (j==3)?1.f:0.f;
#pragma unroll
    for (int n = 0; n < LCH; n++) {
      float h = fmaf(na1, r1, fmaf(na2, r2, fmaf(na3, r3, na4 * r4)));
      r4 = r3; r3 = r2; r2 = r1; r1 = h;
    }
    float c0 = __shfl(r1, j), c1 = __shfl(r2, j),
          c2 = __shfl(r3, j), c3 = __shfl(r4, j);
    float Pv = (i==0)?c0 : (i==1)?c1 : (i==2)?c2 : c3;
    if (c < 16) P[0][c] = Pv;
#pragma unroll
    for (int k = 0; k < 9; k++) {
      float rA0 = __shfl(Pv, i*4+0), rA1 = __shfl(Pv, i*4+1),
            rA2 = __shfl(Pv, i*4+2), rA3 = __shfl(Pv, i*4+3);
      float cB0 = __shfl(Pv, 0*4+j), cB1 = __shfl(Pv, 1*4+j),
            cB2 = __shfl(Pv, 2*4+j), cB3 = __shfl(Pv, 3*4+j);
      Pv = rA0*cB0 + rA1*cB1 + rA2*cB2 + rA3*cB3;
      if (c < 16) P[k+1][c] = Pv;
    }
  }

  // ---------- staged load: global float4 g lands at stage float4 g
  // stage float4 g holds padded p = 12288*s - 5 + 4g + e
  float w4v, w3v, w2v, w1v;
  float A[LCH];
  for (int s = 0; s < 4; s++) {
    __syncthreads();
#pragma unroll
    for (int j = 0; j < 4; j++) {
      int g = 1024*j + c;
      if (g < 3074) {
        float4 v = R[j];
        bool slow = (s == 0 && g <= 4) || (s == 3 && g >= 2789);
        if (slow) {
          float x0d = 2.f * xs[0], xld = 2.f * xs[T48-1];
#pragma unroll
          for (int e = 0; e < 4; e++) {
            int p = 12288*s - 5 + 4*g + e;
            float vv = 0.f;
            if (s == 0) { if (p >= 0) vv = x0d - xs[14 - p]; }
            else        { if (p < TP0) vv = xld - xs[96012 - p]; }
            if (e == 0) v.x = vv; else if (e == 1) v.y = vv;
            else if (e == 2) v.z = vv; else v.w = vv;
          }
        }
        U4[g + g/12] = v;
      }
    }
    if (s < 3) {   // pre-issue next section
#pragma unroll
      for (int j = 0; j < 4; j++) {
        int g = 1024*j + c;
        if (g < 3074) { int m = min(max(3072*(s+1) - 5 + g, 0), 11999); R[j] = xs4[m]; }
      }
    }
    __syncthreads();
    if ((c >> 8) == s) {
      const int cl = c & 255;
      float4 F[14];
#pragma unroll
      for (int k = 0; k < 14; k++)
        F[k] = U4[13*cl + k + (k >= 12 ? 1 : 0)];
      w4v = F[0].y; w3v = F[0].z; w2v = F[0].w; w1v = F[1].x;
#pragma unroll
      for (int n = 0; n < LCH; n++) A[n] = fget(F[(n + 5) >> 2], (n + 5) & 3);
    }
  }
  __syncthreads();   // extraction reads done before scan overwrites U

  // ---------- forward phase 1 (in place, zero-state)
  float r1 = 0.f, r2 = 0.f, r3 = 0.f, r4 = 0.f;
#pragma unroll
  for (int n = 0; n < LCH; n++) {
    float xv = A[n];
    float f = fmaf(b0,xv, fmaf(b1,w1v, fmaf(b2,w2v, fmaf(b3,w3v, b4*w4v))));
    w4v = w3v; w3v = w2v; w2v = w1v; w1v = xv;
    float u = fmaf(na4, r4, f);
    u = fmaf(na3, r3, u); u = fmaf(na2, r2, u); u = fmaf(na1, r1, u);
    A[n] = u; r4 = r3; r3 = r2; r2 = r1; r1 = u;
  }

  // ---------- forward chunk-scan (ping-pong float4)
  float4* Sb0 = U4;
  float4* Sb1 = U4 + 1024;
  Sb0[c] = make_float4(r1, r2, r3, r4);
  __syncthreads();
#pragma unroll
  for (int k = 0; k < 10; k++) {
    float4* cur = (k & 1) ? Sb1 : Sb0;
    float4* nxt = (k & 1) ? Sb0 : Sb1;
    const int off = 1 << k;
    float4 t = cur[c];
    if (c >= off) {
      float4 q = cur[c - off];
      t.x += P[k][0]*q.x  + P[k][1]*q.y  + P[k][2]*q.z  + P[k][3]*q.w;
      t.y += P[k][4]*q.x  + P[k][5]*q.y  + P[k][6]*q.z  + P[k][7]*q.w;
      t.z += P[k][8]*q.x  + P[k][9]*q.y  + P[k][10]*q.z + P[k][11]*q.w;
      t.w += P[k][12]*q.x + P[k][13]*q.y + P[k][14]*q.z + P[k][15]*q.w;
    }
    nxt[c] = t;
    __syncthreads();
  }
  float4 sv = make_float4(0.f,0.f,0.f,0.f);
  if (c > 0) sv = Sb0[c-1];

  // ---------- forward phase 2: homogeneous correction
  {
    float h1 = sv.x, h2 = sv.y, h3 = sv.z, h4 = sv.w;
#pragma unroll
    for (int n = 0; n < LCH; n++) {
      float h = fmaf(na1, h1, fmaf(na2, h2, fmaf(na3, h3, na4 * h4)));
      A[n] += h;
      h4 = h3; h3 = h2; h2 = h1; h1 = h;
    }
  }
  // exact zero tail past TP0
  if (c >= 1000) {
#pragma unroll
    for (int n = 0; n < LCH; n++) if (48*c + n >= TP0) A[n] = 0.f;
  }

  // ---------- exchange heads (backward FIR halo)
  Sb1[c] = make_float4(A[0], A[1], A[2], A[3]);
  __syncthreads();
  float h0 = 0.f, h1v = 0.f, h2v = 0.f, h3v = 0.f;
  if (c < NCH - 1) { float4 hv = Sb1[c+1]; h0 = hv.x; h1v = hv.y; h2v = hv.z; h3v = hv.w; }

  // ---------- backward phase 1 (own chunk reversed, in place)
#define YV(i) ((i) < 48 ? A[(i)] : ((i)==48 ? h0 : (i)==49 ? h1v : (i)==50 ? h2v : h3v))
  r1 = 0.f; r2 = 0.f; r3 = 0.f; r4 = 0.f;
#pragma unroll
  for (int m = 0; m < LCH; m++) {
    float g = fmaf(b0, YV(47-m), fmaf(b1, YV(48-m),
              fmaf(b2, YV(49-m), fmaf(b3, YV(50-m), b4 * YV(51-m)))));
    float u = fmaf(na4, r4, g);
    u = fmaf(na3, r3, u); u = fmaf(na2, r2, u); u = fmaf(na1, r1, u);
    r4 = r3; r3 = r2; r2 = r1; r1 = u;
    if      (m == 0) h3v = u;
    else if (m == 1) h2v = u;
    else if (m == 2) h1v = u;
    else if (m == 3) h0  = u;
    else             A[51 - m] = u;
  }
#undef YV
  // z[0]=h3v z[1]=h2v z[2]=h1v z[3]=h0 ; z[m]=A[51-m] for m>=4

  // ---------- backward chunk-scan
  const int d = NCH - 1 - c;
  Sb0[d] = make_float4(r1, r2, r3, r4);
  __syncthreads();
#pragma unroll
  for (int k = 0; k < 10; k++) {
    float4* cur = (k & 1) ? Sb1 : Sb0;
    float4* nxt = (k & 1) ? Sb0 : Sb1;
    const int off = 1 << k;
    float4 t = cur[d];
    if (d >= off) {
      float4 q = cur[d - off];
      t.x += P[k][0]*q.x  + P[k][1]*q.y  + P[k][2]*q.z  + P[k][3]*q.w;
      t.y += P[k][4]*q.x  + P[k][5]*q.y  + P[k][6]*q.z  + P[k][7]*q.w;
      t.z += P[k][8]*q.x  + P[k][9]*q.y  + P[k][10]*q.z + P[k][11]*q.w;
      t.w += P[k][12]*q.x + P[k][13]*q.y + P[k][14]*q.z + P[k][15]*q.w;
    }
    nxt[d] = t;
    __syncthreads();
  }
  float4 ev = make_float4(0.f,0.f,0.f,0.f);
  if (d > 0) ev = Sb0[d-1];

  // ---------- backward phase 2
  {
    float g1 = ev.x, g2 = ev.y, g3 = ev.z, g4 = ev.w;
#pragma unroll
    for (int m = 0; m < LCH; m++) {
      float h = fmaf(na1, g1, fmaf(na2, g2, fmaf(na3, g3, na4 * g4)));
      if      (m == 0) h3v += h;
      else if (m == 1) h2v += h;
      else if (m == 2) h1v += h;
      else if (m == 3) h0  += h;
      else             A[51 - m] += h;
      g4 = g3; g3 = g2; g2 = g1; g1 = h;
    }
  }

  // ---------- store staging: u = t + 3; thread c owns u4 in [12c-3, 12c+9)
  // slot k4 (u4 = 12c-3+k4) = (z[47-4k4], z[46-4k4], z[45-4k4], z[44-4k4])
  //   = (A[4k4+4..4k4+7]) for k4<=10 ; k4==11 -> (h0, h1v, h2v, h3v)
  __syncthreads();   // ev reads done before store-stage writes
  for (int s = 0; s < 4; s++) {
#pragma unroll
    for (int k4 = 0; k4 < 12; k4++) {
      int u4 = 12*c - 3 + k4;
      unsigned lu4 = (unsigned)(u4 - 3000*s);
      if (lu4 <= 3000u) {
        float4 v;
        if (k4 < 11) v = make_float4(A[4*k4+4], A[4*k4+5], A[4*k4+6], A[4*k4+7]);
        else         v = make_float4(h0, h1v, h2v, h3v);
        U4[(int)lu4 + (int)lu4/12] = v;
      }
    }
    __syncthreads();
#pragma unroll
    for (int j = 0; j < 3; j++) {
      int t4l = 1024*j + c;
      if (t4l < 3000) {
        int q0 = t4l, q1 = t4l + 1;
        int a0 = 4*(q0 + q0/12) + 3;
        int bi = 4*(q1 + q1/12);
        float4 v;
        v.x = U[a0]; v.y = U[bi]; v.z = U[bi+1]; v.w = U[bi+2];
        os4[3000*s + t4l] = v;
      }
    }
    __syncthreads();
  }
}

extern "C" void kernel_launch(void* const* d_in, const int* in_sizes, int n_in,
                              void* d_out, int out_size, void* d_ws, size_t ws_size,
                              hipStream_t stream) {
  (void)n_in; (void)d_ws; (void)ws_size; (void)out_size;
  const float* x = (const float*)d_in[0];
  const float* b = (const float*)d_in[1];
  const float* a = (const float*)d_in[2];
  float* out = (float*)d_out;
  const int nseq = in_sizes[0] / T48;   // 512
  filtfilt_k<<<dim3(nseq), dim3(1024), 0, stream>>>(x, b, a, out);
}